// Round 16
// baseline (500.666 us; speedup 1.0000x reference)
//
#include <hip/hip_runtime.h>
#include <stdint.h>

#define HEADS 6
#define NN 2048
#define BB 4
#define MTOT (BB*NN)   // 8192 rows
#define DEPTH 4

typedef unsigned short u16;
typedef __attribute__((ext_vector_type(8))) short bf16x8;
typedef __attribute__((ext_vector_type(4))) float f32x4;
typedef __attribute__((ext_vector_type(16))) float f32x16;

#define MFMA32(a,b,c) __builtin_amdgcn_mfma_f32_32x32x16_bf16((a),(b),(c),0,0,0)

// scale * log2(e): fold softmax scaling into Q at QKV-epilogue time
#define QSC 0.18033688011112042f

__device__ __forceinline__ u16 f2bf(float f) {
  union { float f; uint32_t u; } v; v.f = f;
  uint32_t r = v.u + 0x7fffu + ((v.u >> 16) & 1u);
  return (u16)(r >> 16);
}

__device__ __forceinline__ uint32_t pk2(float lo, float hi) {
  uint32_t r;
  asm("v_cvt_pk_bf16_f32 %0, %1, %2" : "=v"(r) : "v"(lo), "v"(hi));
  return r;
}

__device__ __forceinline__ void gload_lds16(const void* g, void* l) {
  __builtin_amdgcn_global_load_lds((const __attribute__((address_space(1))) void*)g,
                                   (__attribute__((address_space(3))) void*)l, 16, 0, 0);
}

// ---------------- weight transpose+convert: in[K][N] f32 -> out[N][K] bf16 ----
__global__ __launch_bounds__(256)
void wtrans_k(const float* __restrict__ in, u16* __restrict__ out, int K, int N) {
  __shared__ float t[32][33];
  const int z = blockIdx.z;
  in  += (size_t)z * K * N;
  out += (size_t)z * K * N;
  const int n0 = blockIdx.x * 32, k0 = blockIdx.y * 32;
  const int tx = threadIdx.x & 31, ty = threadIdx.x >> 5;   // 32 x 8
#pragma unroll
  for (int i = 0; i < 4; ++i)
    t[ty + i*8][tx] = in[(size_t)(k0 + ty + i*8) * N + n0 + tx];
  __syncthreads();
#pragma unroll
  for (int i = 0; i < 4; ++i)
    out[(size_t)(n0 + ty + i*8) * K + k0 + tx] = f2bf(t[tx][ty + i*8]);
}

// ---------------- x f32 -> bf16 --------------------------------------------
__global__ __launch_bounds__(256)
void xprep_k(const float* __restrict__ x, u16* __restrict__ xbf, int n) {
  int i = blockIdx.x * 256 + threadIdx.x;
  if (i < n) xbf[i] = f2bf(x[i]);
}

// ---------------- GEMM 64x64 tile, 4 waves (round-8 config + XCD remap) -----
// 16KB LDS single-buffer -> 8 blocks/CU = full 32-wave occupancy; TLP hides
// staging latency (rounds 9/10/14: dbuf / bigger tiles / ILP all regress).
template<int MODE>
__global__ __launch_bounds__(256)
void gemm64_k(const u16* __restrict__ A, const u16* __restrict__ Bt,
              const float* __restrict__ bias, const float* __restrict__ res,
              float* __restrict__ outF, u16* __restrict__ outB,
              u16* __restrict__ qb, u16* __restrict__ kb, u16* __restrict__ vtb,
              int M, int N, int K) {
  __shared__ u16 smA[64 * 64];
  __shared__ u16 smB[64 * 64];
  const int tid = threadIdx.x;
  const int lane = tid & 63, wv = tid >> 6;
  const int wr = wv >> 1, wc = wv & 1;
  const int l31 = lane & 31, h2 = lane >> 5;

  // XCD-chunked bijective remap (nwg % 8 == 0 for all grids used)
  const int gx = gridDim.x;
  const int lid = blockIdx.y * gx + blockIdx.x;
  const int chunk = (gx * gridDim.y) >> 3;
  const int v_ = (lid & 7) * chunk + (lid >> 3);
  const int row0 = (v_ / gx) * 64, col0 = (v_ % gx) * 64;

  f32x16 acc;
#pragma unroll
  for (int i = 0; i < 16; ++i) acc[i] = 0.f;

  const int c0 = tid, c1 = tid + 256;
  const int r0 = c0 >> 3, s0 = (c0 & 7) ^ (r0 & 7);
  const int r1 = c1 >> 3, s1 = (c1 & 7) ^ (r1 & 7);

  const int ksteps = K >> 6;
  for (int kt = 0; kt < ksteps; ++kt) {
    const int k0 = kt << 6;
    const u16* Ab = A  + (size_t)row0 * K + k0;
    const u16* Bb = Bt + (size_t)col0 * K + k0;
    gload_lds16(Ab + (size_t)r0 * K + s0 * 8, smA + wv * 512);
    gload_lds16(Ab + (size_t)r1 * K + s1 * 8, smA + 2048 + wv * 512);
    gload_lds16(Bb + (size_t)r0 * K + s0 * 8, smB + wv * 512);
    gload_lds16(Bb + (size_t)r1 * K + s1 * 8, smB + 2048 + wv * 512);
    __syncthreads();
    const int ra = wr * 32 + l31;
    const int rb = wc * 32 + l31;
#pragma unroll
    for (int ks = 0; ks < 4; ++ks) {
      bf16x8 af = *(const bf16x8*)(smA + ra * 64 + (((ks * 2 + h2) ^ (ra & 7)) * 8));
      bf16x8 bf = *(const bf16x8*)(smB + rb * 64 + (((ks * 2 + h2) ^ (rb & 7)) * 8));
      acc = MFMA32(af, bf, acc);
    }
    __syncthreads();
  }

  // C/D 32x32 layout: col = l31, row = 8*c + 4*h2 + j  (reg = 4c+j)
  const int col = col0 + wc * 32 + l31;
  if (MODE == 0) {
    const int sec = col / 384, c3 = col - sec * 384;
    const int hh = c3 >> 6, d = c3 & 63;
#pragma unroll
    for (int c = 0; c < 4; ++c)
#pragma unroll
      for (int j = 0; j < 4; ++j) {
        const int row = row0 + wr * 32 + 8 * c + 4 * h2 + j;
        const int bb = row >> 11, n = row & 2047;
        const float v = acc[4 * c + j];
        if (sec == 0)       qb [(((size_t)bb * HEADS + hh) * NN + n) * 64 + d] = f2bf(v * QSC);
        else if (sec == 1)  kb [(((size_t)bb * HEADS + hh) * NN + n) * 64 + d] = f2bf(v);
        else                vtb[(((size_t)bb * HEADS + hh) * 64 + d) * NN + n] = f2bf(v);
      }
  } else {
#pragma unroll
    for (int c = 0; c < 4; ++c)
#pragma unroll
      for (int j = 0; j < 4; ++j) {
        const int row = row0 + wr * 32 + 8 * c + 4 * h2 + j;
        float v = acc[4 * c + j];
        if (MODE == 1) {
          size_t idx = (size_t)row * N + col;
          v += res[idx];
          outF[idx] = v;
          outB[idx] = f2bf(v);
        } else if (MODE == 2) {
          v += bias[col];
          v = 0.5f * v * (1.0f + erff(v * 0.70710678118f));
          outB[(size_t)row * N + col] = f2bf(v);
        } else {
          size_t idx = (size_t)row * N + col;
          v += bias[col] + res[idx];
          outF[idx] = v;
          outB[idx] = f2bf(v);
        }
      }
  }
}

// ---------------- flash attention v12: v11 + s_setprio around MFMA (T5) -----
// Grid (32, 24) = 768 blocks (3/CU). Block = 256 thr (4 waves), 64 q-rows.
// Waves {0,1}: q-groups {0,1}, keys 0..1023. Waves {2,3}: same q, keys 1024+.
// Two K/V LDS streams, 32-key tiles, 3-buffer cyclic, PV lags one tile.
// MFMA cluster (QK+PV, 8 back-to-back) wrapped in setprio(1): waves at
// different phases -> scheduler favors the MFMA-issuing wave (m191 regime).
__global__ __launch_bounds__(256)
void attn_k(const u16* __restrict__ qb, const u16* __restrict__ kb,
            const u16* __restrict__ vtb, u16* __restrict__ ob) {
  __shared__ u16 kb3[3][2][32 * 64];   // [buf][half][key][d]   24KB
  __shared__ u16 vb3[3][2][64 * 32];   // [buf][half][d][key]   24KB
  const int tid = threadIdx.x;
  const int lane = tid & 63, wv = tid >> 6;
  const int l31 = lane & 31, h2 = lane >> 5;
  const int hs = wv >> 1;              // key-half this wave consumes
  const int qg = wv & 1;               // q-group this wave computes

  // bijective XCD swizzle: 768 blocks = 8 xcd * (3 bh * 32 qblk)
  const int lid = blockIdx.y * 32 + blockIdx.x;
  const int xcd = lid & 7, ii = lid >> 3;
  const int bh = 3 * xcd + (ii >> 5);
  const int qblk = ii & 31;
  const int b = bh / HEADS, h = bh - b * HEADS;
  const int q0 = qblk * 64 + qg * 32;

  const u16* Qb = qb + ((size_t)bh * NN + q0 + l31) * 64;
  bf16x8 qf[4];
#pragma unroll
  for (int ct2 = 0; ct2 < 4; ++ct2)
    qf[ct2] = *(const bf16x8*)(Qb + ct2 * 16 + h2 * 8);

  float m = -1e30f, s = 0.f;
  f32x16 acc[2];
#pragma unroll
  for (int dg = 0; dg < 2; ++dg)
#pragma unroll
    for (int i = 0; i < 16; ++i) acc[dg][i] = 0.f;
  const f32x16 zero16 = {0.f,0.f,0.f,0.f,0.f,0.f,0.f,0.f,0.f,0.f,0.f,0.f,0.f,0.f,0.f,0.f};

  const u16* Kb0 = kb  + (size_t)bh * NN * 64;
  const u16* Vt0 = vtb + (size_t)bh * 64 * NN;
  const int rK = tid >> 3, sK = (tid & 7) ^ (rK & 7);
  const int rV = tid >> 2, sV = (tid & 3) ^ ((rV >> 1) & 3);   // V involution (r15)

#define STAGE3(kd, vd, t) do { \
    _Pragma("unroll") \
    for (int hf = 0; hf < 2; ++hf) { \
      gload_lds16(Kb0 + ((size_t)(hf * 1024 + (t) * 32 + rK)) * 64 + sK * 8, \
                  (kd) + hf * 2048 + wv * 512); \
      gload_lds16(Vt0 + (size_t)rV * NN + hf * 1024 + (t) * 32 + sV * 8, \
                  (vd) + hf * 2048 + wv * 512); \
    } \
  } while (0)

  u16 *kA = &kb3[0][0][0], *kB = &kb3[1][0][0], *kC = &kb3[2][0][0];
  u16 *vA = &vb3[0][0][0], *vB = &vb3[1][0][0], *vC = &vb3[2][0][0];

  STAGE3(kA, vA, 0);
  __syncthreads();

  bf16x8 pf[2];
  const int NT = 1024 / 32;   // 32 tiles per key-half
  for (int kt = 0; kt < NT; ++kt) {
    if (kt + 1 < NT) STAGE3(kB, vB, kt + 1);

    // MFMA cluster: QK^T(kt) + PV(kt-1) under raised priority (T5)
    __builtin_amdgcn_s_setprio(1);
    f32x16 st = zero16;
    {
      const u16* krow = kA + hs * 2048 + l31 * 64;
#pragma unroll
      for (int ct2 = 0; ct2 < 4; ++ct2) {
        bf16x8 kf = *(const bf16x8*)(krow + (((ct2 * 2 + h2) ^ (l31 & 7)) * 8));
        st = MFMA32(kf, qf[ct2], st);
      }
    }
    if (kt > 0) {
#pragma unroll
      for (int ks = 0; ks < 2; ++ks)
#pragma unroll
        for (int dg = 0; dg < 2; ++dg) {
          const int d = dg * 32 + l31;
          bf16x8 vf = *(const bf16x8*)(vC + hs * 2048 + d * 32 + (((ks * 2 + h2) ^ ((d >> 1) & 3)) * 8));
          acc[dg] = MFMA32(vf, pf[ks], acc[dg]);
        }
    }
    __builtin_amdgcn_s_setprio(0);

    // softmax(kt), log2 domain (Q pre-scaled), deferred rescale
    float t01 = fmaxf(st[0], st[1]),   t23 = fmaxf(st[2], st[3]);
    float t45 = fmaxf(st[4], st[5]),   t67 = fmaxf(st[6], st[7]);
    float t89 = fmaxf(st[8], st[9]),   tab = fmaxf(st[10], st[11]);
    float tcd = fmaxf(st[12], st[13]), tef = fmaxf(st[14], st[15]);
    float tmax = fmaxf(fmaxf(fmaxf(t01, t23), fmaxf(t45, t67)),
                       fmaxf(fmaxf(t89, tab), fmaxf(tcd, tef)));
    if (!__all(tmax <= m + 8.0f)) {
      float rm = fmaxf(tmax, __shfl_xor(tmax, 32));
      float mn = fmaxf(m, rm);
      float al = __builtin_amdgcn_exp2f(m - mn);
      s *= al;
#pragma unroll
      for (int dg = 0; dg < 2; ++dg)
#pragma unroll
        for (int i = 0; i < 16; ++i) acc[dg][i] *= al;
      m = mn;
    }
    float p[16];
    float r = 0.f;
#pragma unroll
    for (int i = 0; i < 16; ++i) {
      float t = __builtin_amdgcn_exp2f(st[i] - m);
      p[i] = t;
      r += t;
    }
    r += __shfl_xor(r, 32);
    s += r;

    // P B-frags (T12): key-offset o at reg=(o>>3)*4+(o&3), half=(o>>2)&1
#pragma unroll
    for (int sub = 0; sub < 2; ++sub) {
      const int s8 = sub * 8;
      uint32_t X0 = pk2(p[s8 + 0], p[s8 + 1]);
      uint32_t X1 = pk2(p[s8 + 2], p[s8 + 3]);
      uint32_t Y0 = pk2(p[s8 + 4], p[s8 + 5]);
      uint32_t Y1 = pk2(p[s8 + 6], p[s8 + 7]);
      asm volatile("v_permlane32_swap_b32 %0, %1" : "+v"(X0), "+v"(Y0));
      asm volatile("v_permlane32_swap_b32 %0, %1" : "+v"(X1), "+v"(Y1));
      union { uint32_t u[4]; bf16x8 v; } pu;
      pu.u[0] = X0; pu.u[1] = X1; pu.u[2] = Y0; pu.u[3] = Y1;
      pf[sub] = pu.v;
    }

    __syncthreads();   // stage(kt+1) landed; all reads of kt done
    u16* t1 = kA; kA = kB; kB = kC; kC = t1;
    u16* t2 = vA; vA = vB; vB = vC; vC = t2;
  }

  // final PV(NT-1): its V sits in vC after the last rotation
  __builtin_amdgcn_s_setprio(1);
#pragma unroll
  for (int ks = 0; ks < 2; ++ks)
#pragma unroll
    for (int dg = 0; dg < 2; ++dg) {
      const int d = dg * 32 + l31;
      bf16x8 vf = *(const bf16x8*)(vC + hs * 2048 + d * 32 + (((ks * 2 + h2) ^ ((d >> 1) & 3)) * 8));
      acc[dg] = MFMA32(vf, pf[ks], acc[dg]);
    }
  __builtin_amdgcn_s_setprio(0);

  // ---- intra-block key-split merge (kb3 is dead; reuse as f32 buffer) ----
  float* mb = (float*)kb3;   // need 128*36 = 4608 floats; have 6144
  if (wv >= 2) {
    const int base = ((wv - 2) * 64 + lane) * 36;
#pragma unroll
    for (int dg = 0; dg < 2; ++dg)
#pragma unroll
      for (int i = 0; i < 16; ++i) mb[base + dg * 16 + i] = acc[dg][i];
    mb[base + 32] = m;
    mb[base + 33] = s;
  }
  __syncthreads();
  if (wv < 2) {
    const int base = (wv * 64 + lane) * 36;
    const float m2 = mb[base + 32], s2 = mb[base + 33];
    const float M  = fmaxf(m, m2);
    const float a1 = __builtin_amdgcn_exp2f(m  - M);
    const float a2 = __builtin_amdgcn_exp2f(m2 - M);
    const float inv = 1.f / (s * a1 + s2 * a2);
    u16* orow = ob + ((size_t)b * NN + q0 + l31) * 384 + h * 64;
#pragma unroll
    for (int dg = 0; dg < 2; ++dg)
#pragma unroll
      for (int c = 0; c < 4; ++c) {
        float v0 = (acc[dg][4*c + 0] * a1 + mb[base + dg*16 + 4*c + 0] * a2) * inv;
        float v1 = (acc[dg][4*c + 1] * a1 + mb[base + dg*16 + 4*c + 1] * a2) * inv;
        float v2 = (acc[dg][4*c + 2] * a1 + mb[base + dg*16 + 4*c + 2] * a2) * inv;
        float v3 = (acc[dg][4*c + 3] * a1 + mb[base + dg*16 + 4*c + 3] * a2) * inv;
        uint2 w;
        w.x = pk2(v0, v1);
        w.y = pk2(v2, v3);
        *(uint2*)(orow + dg * 32 + 8 * c + 4 * h2) = w;
      }
  }
}

// ---------------------------------------------------------------------------
extern "C" void kernel_launch(void* const* d_in, const int* in_sizes, int n_in,
                              void* d_out, int out_size, void* d_ws, size_t ws_size,
                              hipStream_t stream) {
  (void)in_sizes; (void)n_in; (void)out_size; (void)ws_size;
  const float* x    = (const float*)d_in[0];
  const float* Wqkv = (const float*)d_in[1];
  const float* Wout = (const float*)d_in[2];
  const float* W1   = (const float*)d_in[3];
  const float* b1   = (const float*)d_in[4];
  const float* W2   = (const float*)d_in[5];
  const float* b2   = (const float*)d_in[6];
  float* out = (float*)d_out;

  char* ws = (char*)d_ws;
  size_t off = 0;
  auto alloc = [&](size_t bytes) { char* p = ws + off; off += (bytes + 255) & ~(size_t)255; return p; };
  u16*   wqkvT = (u16*)alloc((size_t)DEPTH * 1152 * 384 * 2);
  u16*   woutT = (u16*)alloc((size_t)DEPTH * 384 * 384 * 2);
  u16*   w1T   = (u16*)alloc((size_t)DEPTH * 1536 * 384 * 2);
  u16*   w2T   = (u16*)alloc((size_t)DEPTH * 384 * 1536 * 2);
  u16*   xbf   = (u16*)alloc((size_t)MTOT * 384 * 2);
  float* xres  = (float*)alloc((size_t)MTOT * 384 * 4);
  u16*   qbuf  = (u16*)alloc((size_t)MTOT * 384 * 2);
  u16*   kbuf  = (u16*)alloc((size_t)MTOT * 384 * 2);
  u16*   vtbuf = (u16*)alloc((size_t)MTOT * 384 * 2);
  u16*   obuf  = (u16*)alloc((size_t)MTOT * 384 * 2);
  u16*   hbuf  = (u16*)alloc((size_t)MTOT * 1536 * 2);

  wtrans_k<<<dim3(1152/32, 384/32, DEPTH), 256, 0, stream>>>(Wqkv, wqkvT, 384, 1152);
  wtrans_k<<<dim3( 384/32, 384/32, DEPTH), 256, 0, stream>>>(Wout, woutT, 384, 384);
  wtrans_k<<<dim3(1536/32, 384/32, DEPTH), 256, 0, stream>>>(W1,   w1T,   384, 1536);
  wtrans_k<<<dim3( 384/32,1536/32, DEPTH), 256, 0, stream>>>(W2,   w2T,   1536, 384);
  xprep_k<<<(MTOT*384 + 255)/256, 256, 0, stream>>>(x, xbf, MTOT*384);

  for (int l = 0; l < DEPTH; ++l) {
    gemm64_k<0><<<dim3(1152/64, MTOT/64), 256, 0, stream>>>(
        xbf, wqkvT + (size_t)l*1152*384, nullptr, nullptr, nullptr, nullptr,
        qbuf, kbuf, vtbuf, MTOT, 1152, 384);
    attn_k<<<dim3(32, 24), 256, 0, stream>>>(qbuf, kbuf, vtbuf, obuf);
    gemm64_k<1><<<dim3(384/64, MTOT/64), 256, 0, stream>>>(
        obuf, woutT + (size_t)l*384*384, nullptr, (l == 0 ? x : xres), xres, xbf,
        nullptr, nullptr, nullptr, MTOT, 384, 384);
    gemm64_k<2><<<dim3(1536/64, MTOT/64), 256, 0, stream>>>(
        xbf, w1T + (size_t)l*1536*384, b1 + l*1536, nullptr, nullptr, hbuf,
        nullptr, nullptr, nullptr, MTOT, 1536, 384);
    gemm64_k<3><<<dim3(384/64, MTOT/64), 256, 0, stream>>>(
        hbuf, w2T + (size_t)l*384*1536, b2 + l*384, xres,
        (l == DEPTH-1 ? out : xres), xbf,
        nullptr, nullptr, nullptr, MTOT, 384, 1536);
  }
}

// Round 17
// 496.034 us; speedup vs baseline: 1.0093x; 1.0093x over previous
//
#include <hip/hip_runtime.h>
#include <stdint.h>

#define HEADS 6
#define NN 2048
#define BB 4
#define MTOT (BB*NN)   // 8192 rows
#define DEPTH 4

typedef unsigned short u16;
typedef __attribute__((ext_vector_type(8))) short bf16x8;
typedef __attribute__((ext_vector_type(4))) float f32x4;
typedef __attribute__((ext_vector_type(16))) float f32x16;

#define MFMA32(a,b,c) __builtin_amdgcn_mfma_f32_32x32x16_bf16((a),(b),(c),0,0,0)

// scale * log2(e): fold softmax scaling into Q at QKV-epilogue time
#define QSC 0.18033688011112042f

__device__ __forceinline__ u16 f2bf(float f) {
  union { float f; uint32_t u; } v; v.f = f;
  uint32_t r = v.u + 0x7fffu + ((v.u >> 16) & 1u);
  return (u16)(r >> 16);
}

__device__ __forceinline__ uint32_t pk2(float lo, float hi) {
  uint32_t r;
  asm("v_cvt_pk_bf16_f32 %0, %1, %2" : "=v"(r) : "v"(lo), "v"(hi));
  return r;
}

__device__ __forceinline__ void gload_lds16(const void* g, void* l) {
  __builtin_amdgcn_global_load_lds((const __attribute__((address_space(1))) void*)g,
                                   (__attribute__((address_space(3))) void*)l, 16, 0, 0);
}

// ---------------- weight transpose+convert: in[K][N] f32 -> out[N][K] bf16 ----
__global__ __launch_bounds__(256)
void wtrans_k(const float* __restrict__ in, u16* __restrict__ out, int K, int N) {
  __shared__ float t[32][33];
  const int z = blockIdx.z;
  in  += (size_t)z * K * N;
  out += (size_t)z * K * N;
  const int n0 = blockIdx.x * 32, k0 = blockIdx.y * 32;
  const int tx = threadIdx.x & 31, ty = threadIdx.x >> 5;   // 32 x 8
#pragma unroll
  for (int i = 0; i < 4; ++i)
    t[ty + i*8][tx] = in[(size_t)(k0 + ty + i*8) * N + n0 + tx];
  __syncthreads();
#pragma unroll
  for (int i = 0; i < 4; ++i)
    out[(size_t)(n0 + ty + i*8) * K + k0 + tx] = f2bf(t[tx][ty + i*8]);
}

// ---------------- x f32 -> bf16 --------------------------------------------
__global__ __launch_bounds__(256)
void xprep_k(const float* __restrict__ x, u16* __restrict__ xbf, int n) {
  int i = blockIdx.x * 256 + threadIdx.x;
  if (i < n) xbf[i] = f2bf(x[i]);
}

// ---------------- GEMM 64x64 tile, 4 waves (round-8 config + XCD remap) -----
// 16KB LDS single-buffer -> 8 blocks/CU = full 32-wave occupancy; TLP hides
// staging latency (rounds 9/10/14: dbuf / bigger tiles / ILP all regress).
template<int MODE>
__global__ __launch_bounds__(256)
void gemm64_k(const u16* __restrict__ A, const u16* __restrict__ Bt,
              const float* __restrict__ bias, const float* __restrict__ res,
              float* __restrict__ outF, u16* __restrict__ outB,
              u16* __restrict__ qb, u16* __restrict__ kb, u16* __restrict__ vtb,
              int M, int N, int K) {
  __shared__ u16 smA[64 * 64];
  __shared__ u16 smB[64 * 64];
  const int tid = threadIdx.x;
  const int lane = tid & 63, wv = tid >> 6;
  const int wr = wv >> 1, wc = wv & 1;
  const int l31 = lane & 31, h2 = lane >> 5;

  // XCD-chunked bijective remap (nwg % 8 == 0 for all grids used)
  const int gx = gridDim.x;
  const int lid = blockIdx.y * gx + blockIdx.x;
  const int chunk = (gx * gridDim.y) >> 3;
  const int v_ = (lid & 7) * chunk + (lid >> 3);
  const int row0 = (v_ / gx) * 64, col0 = (v_ % gx) * 64;

  f32x16 acc;
#pragma unroll
  for (int i = 0; i < 16; ++i) acc[i] = 0.f;

  const int c0 = tid, c1 = tid + 256;
  const int r0 = c0 >> 3, s0 = (c0 & 7) ^ (r0 & 7);
  const int r1 = c1 >> 3, s1 = (c1 & 7) ^ (r1 & 7);

  const int ksteps = K >> 6;
  for (int kt = 0; kt < ksteps; ++kt) {
    const int k0 = kt << 6;
    const u16* Ab = A  + (size_t)row0 * K + k0;
    const u16* Bb = Bt + (size_t)col0 * K + k0;
    gload_lds16(Ab + (size_t)r0 * K + s0 * 8, smA + wv * 512);
    gload_lds16(Ab + (size_t)r1 * K + s1 * 8, smA + 2048 + wv * 512);
    gload_lds16(Bb + (size_t)r0 * K + s0 * 8, smB + wv * 512);
    gload_lds16(Bb + (size_t)r1 * K + s1 * 8, smB + 2048 + wv * 512);
    __syncthreads();
    const int ra = wr * 32 + l31;
    const int rb = wc * 32 + l31;
#pragma unroll
    for (int ks = 0; ks < 4; ++ks) {
      bf16x8 af = *(const bf16x8*)(smA + ra * 64 + (((ks * 2 + h2) ^ (ra & 7)) * 8));
      bf16x8 bf = *(const bf16x8*)(smB + rb * 64 + (((ks * 2 + h2) ^ (rb & 7)) * 8));
      acc = MFMA32(af, bf, acc);
    }
    __syncthreads();
  }

  // C/D 32x32 layout: col = l31, row = 8*c + 4*h2 + j  (reg = 4c+j)
  const int col = col0 + wc * 32 + l31;
  if (MODE == 0) {
    const int sec = col / 384, c3 = col - sec * 384;
    const int hh = c3 >> 6, d = c3 & 63;
#pragma unroll
    for (int c = 0; c < 4; ++c)
#pragma unroll
      for (int j = 0; j < 4; ++j) {
        const int row = row0 + wr * 32 + 8 * c + 4 * h2 + j;
        const int bb = row >> 11, n = row & 2047;
        const float v = acc[4 * c + j];
        if (sec == 0)       qb [(((size_t)bb * HEADS + hh) * NN + n) * 64 + d] = f2bf(v * QSC);
        else if (sec == 1)  kb [(((size_t)bb * HEADS + hh) * NN + n) * 64 + d] = f2bf(v);
        else                vtb[(((size_t)bb * HEADS + hh) * 64 + d) * NN + n] = f2bf(v);
      }
  } else {
#pragma unroll
    for (int c = 0; c < 4; ++c)
#pragma unroll
      for (int j = 0; j < 4; ++j) {
        const int row = row0 + wr * 32 + 8 * c + 4 * h2 + j;
        float v = acc[4 * c + j];
        if (MODE == 1) {
          size_t idx = (size_t)row * N + col;
          v += res[idx];
          outF[idx] = v;
          outB[idx] = f2bf(v);
        } else if (MODE == 2) {
          v += bias[col];
          v = 0.5f * v * (1.0f + erff(v * 0.70710678118f));
          outB[(size_t)row * N + col] = f2bf(v);
        } else {
          size_t idx = (size_t)row * N + col;
          v += bias[col] + res[idx];
          outF[idx] = v;
          outB[idx] = f2bf(v);
        }
      }
  }
}

// ---------------- flash attention v8 (best measured: 48.2-48.8us) -----------
// Grid (32, 24) = 768 blocks (3/CU). Block = 256 thr (4 waves), 64 q-rows.
// Waves {0,1}: q-groups {0,1}, keys 0..1023. Waves {2,3}: same q, keys 1024+.
// Two K/V LDS streams, 32-key tiles, 3-buffer cyclic, PV lags one tile.
// End: waves 2,3 publish (m,s,acc) via LDS; waves 0,1 merge + write.
__global__ __launch_bounds__(256)
void attn_k(const u16* __restrict__ qb, const u16* __restrict__ kb,
            const u16* __restrict__ vtb, u16* __restrict__ ob) {
  __shared__ u16 kb3[3][2][32 * 64];   // [buf][half][key][d]   24KB
  __shared__ u16 vb3[3][2][64 * 32];   // [buf][half][d][key]   24KB
  const int tid = threadIdx.x;
  const int lane = tid & 63, wv = tid >> 6;
  const int l31 = lane & 31, h2 = lane >> 5;
  const int hs = wv >> 1;              // key-half this wave consumes
  const int qg = wv & 1;               // q-group this wave computes

  // bijective XCD swizzle: 768 blocks = 8 xcd * (3 bh * 32 qblk)
  const int lid = blockIdx.y * 32 + blockIdx.x;
  const int xcd = lid & 7, ii = lid >> 3;
  const int bh = 3 * xcd + (ii >> 5);
  const int qblk = ii & 31;
  const int b = bh / HEADS, h = bh - b * HEADS;
  const int q0 = qblk * 64 + qg * 32;

  const u16* Qb = qb + ((size_t)bh * NN + q0 + l31) * 64;
  bf16x8 qf[4];
#pragma unroll
  for (int ct2 = 0; ct2 < 4; ++ct2)
    qf[ct2] = *(const bf16x8*)(Qb + ct2 * 16 + h2 * 8);

  float m = -1e30f, s = 0.f;
  f32x16 acc[2];
#pragma unroll
  for (int dg = 0; dg < 2; ++dg)
#pragma unroll
    for (int i = 0; i < 16; ++i) acc[dg][i] = 0.f;
  const f32x16 zero16 = {0.f,0.f,0.f,0.f,0.f,0.f,0.f,0.f,0.f,0.f,0.f,0.f,0.f,0.f,0.f,0.f};

  const u16* Kb0 = kb  + (size_t)bh * NN * 64;
  const u16* Vt0 = vtb + (size_t)bh * 64 * NN;
  const int rK = tid >> 3, sK = (tid & 7) ^ (rK & 7);
  const int rV = tid >> 2, sV = (tid & 3) ^ (rV & 3);

#define STAGE3(kd, vd, t) do { \
    _Pragma("unroll") \
    for (int hf = 0; hf < 2; ++hf) { \
      gload_lds16(Kb0 + ((size_t)(hf * 1024 + (t) * 32 + rK)) * 64 + sK * 8, \
                  (kd) + hf * 2048 + wv * 512); \
      gload_lds16(Vt0 + (size_t)rV * NN + hf * 1024 + (t) * 32 + sV * 8, \
                  (vd) + hf * 2048 + wv * 512); \
    } \
  } while (0)

  u16 *kA = &kb3[0][0][0], *kB = &kb3[1][0][0], *kC = &kb3[2][0][0];
  u16 *vA = &vb3[0][0][0], *vB = &vb3[1][0][0], *vC = &vb3[2][0][0];

  STAGE3(kA, vA, 0);
  __syncthreads();

  bf16x8 pf[2];
  const int NT = 1024 / 32;   // 32 tiles per key-half
  for (int kt = 0; kt < NT; ++kt) {
    if (kt + 1 < NT) STAGE3(kB, vB, kt + 1);

    // QK^T(kt): 4 MFMAs from kA (this wave's key-half)
    f32x16 st = zero16;
    {
      const u16* krow = kA + hs * 2048 + l31 * 64;
#pragma unroll
      for (int ct2 = 0; ct2 < 4; ++ct2) {
        bf16x8 kf = *(const bf16x8*)(krow + (((ct2 * 2 + h2) ^ (l31 & 7)) * 8));
        st = MFMA32(kf, qf[ct2], st);
      }
    }
    // PV(kt-1): 4 independent MFMAs from vC
    if (kt > 0) {
#pragma unroll
      for (int ks = 0; ks < 2; ++ks)
#pragma unroll
        for (int dg = 0; dg < 2; ++dg) {
          const int d = dg * 32 + l31;
          bf16x8 vf = *(const bf16x8*)(vC + hs * 2048 + d * 32 + (((ks * 2 + h2) ^ (d & 3)) * 8));
          acc[dg] = MFMA32(vf, pf[ks], acc[dg]);
        }
    }

    // softmax(kt), log2 domain (Q pre-scaled), deferred rescale
    float tmax = -1e30f;
#pragma unroll
    for (int i = 0; i < 16; ++i) tmax = fmaxf(tmax, st[i]);
    if (!__all(tmax <= m + 8.0f)) {
      float rm = fmaxf(tmax, __shfl_xor(tmax, 32));
      float mn = fmaxf(m, rm);
      float al = __builtin_amdgcn_exp2f(m - mn);
      s *= al;
#pragma unroll
      for (int dg = 0; dg < 2; ++dg)
#pragma unroll
        for (int i = 0; i < 16; ++i) acc[dg][i] *= al;
      m = mn;
    }
    float p[16];
    float r = 0.f;
#pragma unroll
    for (int i = 0; i < 16; ++i) {
      float t = __builtin_amdgcn_exp2f(st[i] - m);
      p[i] = t;
      r += t;
    }
    r += __shfl_xor(r, 32);
    s += r;

    // P B-frags (T12): key-offset o at reg=(o>>3)*4+(o&3), half=(o>>2)&1
#pragma unroll
    for (int sub = 0; sub < 2; ++sub) {
      const int s8 = sub * 8;
      uint32_t X0 = pk2(p[s8 + 0], p[s8 + 1]);
      uint32_t X1 = pk2(p[s8 + 2], p[s8 + 3]);
      uint32_t Y0 = pk2(p[s8 + 4], p[s8 + 5]);
      uint32_t Y1 = pk2(p[s8 + 6], p[s8 + 7]);
      asm volatile("v_permlane32_swap_b32 %0, %1" : "+v"(X0), "+v"(Y0));
      asm volatile("v_permlane32_swap_b32 %0, %1" : "+v"(X1), "+v"(Y1));
      union { uint32_t u[4]; bf16x8 v; } pu;
      pu.u[0] = X0; pu.u[1] = X1; pu.u[2] = Y0; pu.u[3] = Y1;
      pf[sub] = pu.v;
    }

    __syncthreads();   // stage(kt+1) landed; all reads of kt done
    u16* t1 = kA; kA = kB; kB = kC; kC = t1;
    u16* t2 = vA; vA = vB; vB = vC; vC = t2;
  }

  // final PV(NT-1): its V sits in vC after the last rotation
#pragma unroll
  for (int ks = 0; ks < 2; ++ks)
#pragma unroll
    for (int dg = 0; dg < 2; ++dg) {
      const int d = dg * 32 + l31;
      bf16x8 vf = *(const bf16x8*)(vC + hs * 2048 + d * 32 + (((ks * 2 + h2) ^ (d & 3)) * 8));
      acc[dg] = MFMA32(vf, pf[ks], acc[dg]);
    }

  // ---- intra-block key-split merge (kb3 is dead; reuse as f32 buffer) ----
  float* mb = (float*)kb3;   // need 128*36 = 4608 floats; have 6144
  if (wv >= 2) {
    const int base = ((wv - 2) * 64 + lane) * 36;
#pragma unroll
    for (int dg = 0; dg < 2; ++dg)
#pragma unroll
      for (int i = 0; i < 16; ++i) mb[base + dg * 16 + i] = acc[dg][i];
    mb[base + 32] = m;
    mb[base + 33] = s;
  }
  __syncthreads();
  if (wv < 2) {
    const int base = (wv * 64 + lane) * 36;
    const float m2 = mb[base + 32], s2 = mb[base + 33];
    const float M  = fmaxf(m, m2);
    const float a1 = __builtin_amdgcn_exp2f(m  - M);
    const float a2 = __builtin_amdgcn_exp2f(m2 - M);
    const float inv = 1.f / (s * a1 + s2 * a2);
    u16* orow = ob + ((size_t)b * NN + q0 + l31) * 384 + h * 64;
#pragma unroll
    for (int dg = 0; dg < 2; ++dg)
#pragma unroll
      for (int c = 0; c < 4; ++c) {
        float v0 = (acc[dg][4*c + 0] * a1 + mb[base + dg*16 + 4*c + 0] * a2) * inv;
        float v1 = (acc[dg][4*c + 1] * a1 + mb[base + dg*16 + 4*c + 1] * a2) * inv;
        float v2 = (acc[dg][4*c + 2] * a1 + mb[base + dg*16 + 4*c + 2] * a2) * inv;
        float v3 = (acc[dg][4*c + 3] * a1 + mb[base + dg*16 + 4*c + 3] * a2) * inv;
        uint2 w;
        w.x = pk2(v0, v1);
        w.y = pk2(v2, v3);
        *(uint2*)(orow + dg * 32 + 8 * c + 4 * h2) = w;
      }
  }
}

// ---------------------------------------------------------------------------
extern "C" void kernel_launch(void* const* d_in, const int* in_sizes, int n_in,
                              void* d_out, int out_size, void* d_ws, size_t ws_size,
                              hipStream_t stream) {
  (void)in_sizes; (void)n_in; (void)out_size; (void)ws_size;
  const float* x    = (const float*)d_in[0];
  const float* Wqkv = (const float*)d_in[1];
  const float* Wout = (const float*)d_in[2];
  const float* W1   = (const float*)d_in[3];
  const float* b1   = (const float*)d_in[4];
  const float* W2   = (const float*)d_in[5];
  const float* b2   = (const float*)d_in[6];
  float* out = (float*)d_out;

  char* ws = (char*)d_ws;
  size_t off = 0;
  auto alloc = [&](size_t bytes) { char* p = ws + off; off += (bytes + 255) & ~(size_t)255; return p; };
  u16*   wqkvT = (u16*)alloc((size_t)DEPTH * 1152 * 384 * 2);
  u16*   woutT = (u16*)alloc((size_t)DEPTH * 384 * 384 * 2);
  u16*   w1T   = (u16*)alloc((size_t)DEPTH * 1536 * 384 * 2);
  u16*   w2T   = (u16*)alloc((size_t)DEPTH * 384 * 1536 * 2);
  u16*   xbf   = (u16*)alloc((size_t)MTOT * 384 * 2);
  float* xres  = (float*)alloc((size_t)MTOT * 384 * 4);
  u16*   qbuf  = (u16*)alloc((size_t)MTOT * 384 * 2);
  u16*   kbuf  = (u16*)alloc((size_t)MTOT * 384 * 2);
  u16*   vtbuf = (u16*)alloc((size_t)MTOT * 384 * 2);
  u16*   obuf  = (u16*)alloc((size_t)MTOT * 384 * 2);
  u16*   hbuf  = (u16*)alloc((size_t)MTOT * 1536 * 2);

  wtrans_k<<<dim3(1152/32, 384/32, DEPTH), 256, 0, stream>>>(Wqkv, wqkvT, 384, 1152);
  wtrans_k<<<dim3( 384/32, 384/32, DEPTH), 256, 0, stream>>>(Wout, woutT, 384, 384);
  wtrans_k<<<dim3(1536/32, 384/32, DEPTH), 256, 0, stream>>>(W1,   w1T,   384, 1536);
  wtrans_k<<<dim3( 384/32,1536/32, DEPTH), 256, 0, stream>>>(W2,   w2T,   1536, 384);
  xprep_k<<<(MTOT*384 + 255)/256, 256, 0, stream>>>(x, xbf, MTOT*384);

  for (int l = 0; l < DEPTH; ++l) {
    gemm64_k<0><<<dim3(1152/64, MTOT/64), 256, 0, stream>>>(
        xbf, wqkvT + (size_t)l*1152*384, nullptr, nullptr, nullptr, nullptr,
        qbuf, kbuf, vtbuf, MTOT, 1152, 384);
    attn_k<<<dim3(32, 24), 256, 0, stream>>>(qbuf, kbuf, vtbuf, obuf);
    gemm64_k<1><<<dim3(384/64, MTOT/64), 256, 0, stream>>>(
        obuf, woutT + (size_t)l*384*384, nullptr, (l == 0 ? x : xres), xres, xbf,
        nullptr, nullptr, nullptr, MTOT, 384, 384);
    gemm64_k<2><<<dim3(1536/64, MTOT/64), 256, 0, stream>>>(
        xbf, w1T + (size_t)l*1536*384, b1 + l*1536, nullptr, nullptr, hbuf,
        nullptr, nullptr, nullptr, MTOT, 1536, 384);
    gemm64_k<3><<<dim3(384/64, MTOT/64), 256, 0, stream>>>(
        hbuf, w2T + (size_t)l*384*1536, b2 + l*384, xres,
        (l == DEPTH-1 ? out : xres), xbf,
        nullptr, nullptr, nullptr, MTOT, 384, 1536);
  }
}